// Round 9
// baseline (107.950 us; speedup 1.0000x reference)
//
#include <hip/hip_runtime.h>
#include <stdint.h>

// Fused NCA step: perception(4 fixed 3x3, wrap) -> 1x1 conv 32->16 +b+ReLU
// -> 1x1 conv 16->8 -> x + y*mask.  fp32, v_pk_fma_f32 (2 px/instr).
// R9 = best-of breeding: R6's 2-phase LDS pipeline (1 ch/phase, 12 KB LDS,
// plain __syncthreads -- measured best at 96us) + R8's residual-capture from
// LDS (epilogue has zero global loads; FETCH 103->74 MB proven) +
// launch_bounds(256,8): VGPR has been 32-40 all along, so the 64-VGPR cap is
// free and lifts occupancy 6->8 waves/SIMD. R6 vs R8 showed occupancy (TLP
// across blocks filling DMA-wait gaps) dominates barrier arithmetic.

constexpr int B = 16, C = 8, H = 512, W = 512, HID = 16;
constexpr int HW = H * W;
constexpr int BUF = 3 * W;   // floats per channel buffer (3 rows, 6 KB)

// acc += w * p   (w uniform SGPR pair {w,w}, p/acc per-lane float2)
#define PKFMA_S(acc, w, p) \
    asm("v_pk_fma_f32 %0, %1, %2, %0" : "+v"(acc) : "s"(w), "v"(p))
// acc += a * b   (all VGPR)
#define PKFMA_V(acc, a, b) \
    asm("v_pk_fma_f32 %0, %1, %2, %0" : "+v"(acc) : "v"(a), "v"(b))

typedef const __attribute__((address_space(1))) void* as1cp;
typedef __attribute__((address_space(3))) void* as3p;

__global__ void repack_weights(const float* __restrict__ w1w,
                               const float* __restrict__ w2w,
                               float2* __restrict__ wd) {
    const int i = blockIdx.x * 256 + threadIdx.x;
    if (i < 512) {               // w1d[c][h][f] = dup(w1w[h][c*4+f])
        const int c = i >> 6, r = i & 63, h = r >> 2, f = r & 3;
        const float v = w1w[h * 32 + c * 4 + f];
        wd[i] = make_float2(v, v);
    } else if (i < 640) {        // w2d[o][h] = dup(w2w[o][h])
        const float v = w2w[i - 512];
        wd[i] = make_float2(v, v);
    }
}

__global__ __launch_bounds__(256, 8) void nca_step_kernel(
    const float* __restrict__ x,
    const float* __restrict__ w1b,
    const int*   __restrict__ mask,
    float*       __restrict__ out,
    const float2* __restrict__ wd)
{
    __shared__ float S[2 * BUF];             // 12 KB: double-buffered 3-row tile

    // block = one image row; XCD-bijective swizzle (8192 = 8 * 1024)
    const int bid = blockIdx.x;
    const int l   = (bid & 7) * 1024 + (bid >> 3);
    const int b   = l >> 9;
    const int y   = l & (H - 1);

    const int tx   = threadIdx.x;
    const int x0   = tx << 1;                // 2 px/thread
    const int lane = tx & 63;
    const int wv   = tx >> 6;                // wave id 0..3 (uniform)

    const int ym = (y - 1) & (H - 1);
    const int yp = (y + 1) & (H - 1);
    const int xm1 = (x0 - 1) & (W - 1);
    const int xp2 = (x0 + 2) & (W - 1);

    const float* xb = x + (size_t)b * C * HW;
    const int pix = y * W + x0;

    // mask: one early direct load; latency hidden under the whole pipeline
    const int2 m2 = *(const int2*)(mask + (size_t)b * HW + pix);

    // Stage geometry: 6 chunks of 1024 B (64 lanes x 16 B) cover 3 rows.
    // Issue 1: waves {0,1}->row ym halves, waves {2,3}->row y halves.
    // Issue 2 (waves 0,1 only): row yp halves.  All wave-uniform.
    const int hh = wv & 1;                         // 256-float half of a row
    const int g1 = ((wv < 2) ? ym : y) * W + hh * 256 + lane * 4;
    const int l1 = ((wv < 2) ? 0 : W) + hh * 256;  // LDS float offset (uniform)
    const int g2 = yp * W + hh * 256 + lane * 4;
    const int l2 = 2 * W + hh * 256;

#define STAGE(ch, bufo) do {                                               \
    const float* cb_ = xb + (ch) * HW;                                     \
    __builtin_amdgcn_global_load_lds((as1cp)(cb_ + g1),                    \
                                     (as3p)(S + (bufo) + l1), 16, 0, 0);   \
    if (wv < 2)                                                            \
        __builtin_amdgcn_global_load_lds((as1cp)(cb_ + g2),                \
                                         (as3p)(S + (bufo) + l2), 16, 0, 0); \
    } while (0)

#define COMPCH(ch, bufo) do {                                              \
    const float* R0 = S + (bufo);                                          \
    const float* R1 = R0 + W;                                              \
    const float* R2 = R1 + W;                                              \
    const float2 vm = *(const float2*)(R0 + x0);                           \
    const float2 vc = *(const float2*)(R1 + x0);                           \
    const float2 vp = *(const float2*)(R2 + x0);                           \
    xs##ch = vc;                      /* residual capture: x[b,ch,y,x0] */ \
    const float cm[4] = {R0[xm1], vm.x, vm.y, R0[xp2]};                    \
    const float cc[4] = {R1[xm1], vc.x, vc.y, R1[xp2]};                    \
    const float cp[4] = {R2[xm1], vp.x, vp.y, R2[xp2]};                    \
    float s_[4], d_[4];                                                    \
    _Pragma("unroll") for (int i = 0; i < 4; ++i) {                        \
        s_[i] = fmaf(2.0f, cc[i], cm[i] + cp[i]);                          \
        d_[i] = cp[i] - cm[i]; }                                           \
    const float sx0  = (s_[2] - s_[0]) * 0.125f;                           \
    const float sx1  = (s_[3] - s_[1]) * 0.125f;                           \
    const float sy0  = fmaf(2.0f, d_[1], d_[0] + d_[2]) * 0.125f;          \
    const float sy1  = fmaf(2.0f, d_[2], d_[1] + d_[3]) * 0.125f;          \
    const float lap0 = fmaf(fmaf(2.0f, s_[1], s_[0] + s_[2]), 0.0625f, -cc[1]); \
    const float lap1 = fmaf(fmaf(2.0f, s_[2], s_[1] + s_[3]), 0.0625f, -cc[2]); \
    const float2 idn2 = make_float2(cc[1], cc[2]);                         \
    const float2 sx2  = make_float2(sx0, sx1);                             \
    const float2 sy2  = make_float2(sy0, sy1);                             \
    const float2 lp2  = make_float2(lap0, lap1);                           \
    const float2* wch = wd + (ch) * 64;                                    \
    _Pragma("unroll") for (int h = 0; h < HID; ++h) {                      \
        PKFMA_S(acc[h], wch[h * 4 + 0], idn2);                             \
        PKFMA_S(acc[h], wch[h * 4 + 1], sx2);                              \
        PKFMA_S(acc[h], wch[h * 4 + 2], sy2);                              \
        PKFMA_S(acc[h], wch[h * 4 + 3], lp2); } } while (0)

    float2 acc[HID];                         // 32 VGPRs, static idx (unrolled)
#pragma unroll
    for (int h = 0; h < HID; ++h) {
        const float bv = w1b[h];             // uniform -> s_load
        acc[h] = make_float2(bv, bv);
    }

    // named residual-capture registers (static, no arrays)
    float2 xs0, xs1, xs2, xs3, xs4, xs5, xs6, xs7;

    // ---- 2-phase channel pipeline: stage c+1 async, compute c from LDS ----
    STAGE(0, 0);
    __syncthreads();                         // vmcnt(0)+lgkmcnt(0)+barrier
    STAGE(1, BUF); COMPCH(0, 0);   __syncthreads();
    STAGE(2, 0);   COMPCH(1, BUF); __syncthreads();
    STAGE(3, BUF); COMPCH(2, 0);   __syncthreads();
    STAGE(4, 0);   COMPCH(3, BUF); __syncthreads();
    STAGE(5, BUF); COMPCH(4, 0);   __syncthreads();
    STAGE(6, 0);   COMPCH(5, BUF); __syncthreads();
    STAGE(7, BUF); COMPCH(6, 0);   __syncthreads();
                   COMPCH(7, BUF);

#undef STAGE
#undef COMPCH

    // ReLU
#pragma unroll
    for (int h = 0; h < HID; ++h) {
        acc[h].x = fmaxf(acc[h].x, 0.0f);
        acc[h].y = fmaxf(acc[h].y, 0.0f);
    }

    const float2 mf = make_float2((float)m2.x, (float)m2.y);
    const float2* w2d = wd + 512;
    float* ob = out + (size_t)b * C * HW;

    // epilogue: conv2 + masked residual add -- ZERO global loads
#define EPI(o, xsv) do {                                                   \
    float2 v = make_float2(0.0f, 0.0f);                                    \
    _Pragma("unroll") for (int h = 0; h < HID; ++h)                        \
        PKFMA_S(v, w2d[(o) * 16 + h], acc[h]);                             \
    float2 r = xsv;                                                        \
    PKFMA_V(r, v, mf);                    /* r = x + conv2 * mask */       \
    *(float2*)(ob + (o) * HW + pix) = r; } while (0)

    EPI(0, xs0); EPI(1, xs1); EPI(2, xs2); EPI(3, xs3);
    EPI(4, xs4); EPI(5, xs5); EPI(6, xs6); EPI(7, xs7);
#undef EPI
}

extern "C" void kernel_launch(void* const* d_in, const int* in_sizes, int n_in,
                              void* d_out, int out_size, void* d_ws, size_t ws_size,
                              hipStream_t stream) {
    const float* x    = (const float*)d_in[0];
    const float* w1w  = (const float*)d_in[1];
    const float* w1b  = (const float*)d_in[2];
    const float* w2w  = (const float*)d_in[3];
    const int*   mask = (const int*)d_in[4];
    float* out = (float*)d_out;
    float2* wd = (float2*)d_ws;              // 640 * 8 B = 5 KiB scratch

    hipLaunchKernelGGL(repack_weights, dim3(3), dim3(256), 0, stream,
                       w1w, w2w, wd);
    hipLaunchKernelGGL(nca_step_kernel, dim3(B * H), dim3(256), 0, stream,
                       x, w1b, mask, out, wd);
}

// Round 10
// 96.989 us; speedup vs baseline: 1.1130x; 1.1130x over previous
//
#include <hip/hip_runtime.h>
#include <stdint.h>

// Fused NCA step: perception(4 fixed 3x3, wrap) -> 1x1 conv 32->16 +b+ReLU
// -> 1x1 conv 16->8 -> x + y*mask.  fp32, v_pk_fma_f32 (2 px/instr).
// R10: R6 (96us) exposed DMA latency each barrier (compute 650 < DMA 900cyc);
// R8 fixed the ratio but killed occupancy; R9's capture spilled under lb(,8).
// Now: 512-thread block = row PAIR, 2 channels/phase (compute 1300 > 900),
// 4 barriers, 16 KB/buffer (2ch x 4rows), 2 DMAs/wave uniform, NO capture
// (epilogue re-loads x, keeps VGPR <= 64), lb(512,8) -> 32 waves/CU.
// Filter scales + lap's -ident folded into repacked W1 (free VALU cut).

constexpr int B = 16, C = 8, H = 512, W = 512, HID = 16;
constexpr int HW  = H * W;
constexpr int CHF = 4 * W;        // floats per channel per buffer (4 rows)
constexpr int BUF = 2 * CHF;      // 2-channel buffer = 4096 floats (16 KB)

// acc += w * p   (w uniform SGPR pair {w,w}, p/acc per-lane float2)
#define PKFMA_S(acc, w, p) \
    asm("v_pk_fma_f32 %0, %1, %2, %0" : "+v"(acc) : "s"(w), "v"(p))
// acc += a * b   (all VGPR)
#define PKFMA_V(acc, a, b) \
    asm("v_pk_fma_f32 %0, %1, %2, %0" : "+v"(acc) : "v"(a), "v"(b))

typedef const __attribute__((address_space(1))) void* as1cp;
typedef __attribute__((address_space(3))) void* as3p;

__global__ void repack_weights(const float* __restrict__ w1w,
                               const float* __restrict__ w2w,
                               float2* __restrict__ wd) {
    const int i = blockIdx.x * 256 + threadIdx.x;
    if (i < 512) {       // w1d[c][h][f], scales folded:
        const int c = i >> 6, r = i & 63, h = r >> 2, f = r & 3;
        const float* wr = w1w + h * 32 + c * 4;
        float v;
        if (f == 0)      v = wr[0] - wr[3];        // ident absorbs lap's -ident
        else if (f == 3) v = wr[3] * 0.0625f;      // lap raw scale
        else             v = wr[f] * 0.125f;       // sobel scales
        wd[i] = make_float2(v, v);
    } else if (i < 640) {                          // w2d[o][h] = dup(w2w[o][h])
        const float v = w2w[i - 512];
        wd[i] = make_float2(v, v);
    }
}

__global__ __launch_bounds__(512, 8) void nca_step_kernel(
    const float* __restrict__ x,
    const float* __restrict__ w1b,
    const int*   __restrict__ mask,
    float*       __restrict__ out,
    const float2* __restrict__ wd)
{
    __shared__ float S[2 * BUF];          // 32 KB: double 2-channel buffer

    // block = one row PAIR; XCD-bijective swizzle (4096 = 8 * 512)
    const int bid = blockIdx.x;
    const int l   = (bid & 7) * 512 + (bid >> 3);
    const int b   = l >> 8;
    const int pr  = l & 255;
    const int y0  = pr << 1;
    const int y1  = y0 + 1;

    const int tid  = threadIdx.x;
    const int rel  = tid >> 8;            // 0: row y0, 1: row y1
    const int tx   = tid & 255;
    const int x0   = tx << 1;             // 2 px/thread
    const int lane = tid & 63;
    const int wv   = tid >> 6;            // wave 0..7 (uniform per wave)

    const int ym  = (y0 - 1) & (H - 1);
    const int yp2 = (y1 + 1) & (H - 1);   // y1+1 wraps only at y1=511
    const int xm1 = (x0 - 1) & (W - 1);
    const int xp2 = (x0 + 2) & (W - 1);

    const float* xb = x + (size_t)b * C * HW;
    const int y   = y0 + rel;
    const int pix = y * W + x0;

    // mask early; latency hidden under the whole pipeline
    const int2 m2 = *(const int2*)(mask + (size_t)b * HW + pix);
    const float2 mf = make_float2((float)m2.x, (float)m2.y);

    // per-wave stage geometry: wave wv stages channel (cb + wv>>2),
    // staged-row (wv&3) of {ym, y0, y1, yp2}, both 1 KB halves.
    const int ch_l = wv >> 2;
    const int rr   = wv & 3;
    const int grow = (rr == 0) ? ym : ((rr == 1) ? y0 : ((rr == 2) ? y1 : yp2));
    const int goff = grow * W + lane * 4;       // global float offset (+256)
    const int loff = ch_l * CHF + rr * W;       // LDS float offset (+256)

#define STAGE(cb, bufo) do {                                               \
    const float* s_ = xb + ((cb) + ch_l) * HW + goff;                      \
    float* d_ = S + (bufo) + loff;                                         \
    __builtin_amdgcn_global_load_lds((as1cp)s_, (as3p)d_, 16, 0, 0);       \
    __builtin_amdgcn_global_load_lds((as1cp)(s_ + 256), (as3p)(d_ + 256),  \
                                     16, 0, 0); } while (0)

    // compute channel ch (= weight index) from buffer slot cl of buffer bufo
#define COMPCH(ch, cl, bufo) do {                                          \
    const float* R0 = S + (bufo) + (cl) * CHF + rel * W;                   \
    const float* R1 = R0 + W;                                              \
    const float* R2 = R1 + W;                                              \
    const float2 vm = *(const float2*)(R0 + x0);                           \
    const float2 vc = *(const float2*)(R1 + x0);                           \
    const float2 vp = *(const float2*)(R2 + x0);                           \
    const float cm[4] = {R0[xm1], vm.x, vm.y, R0[xp2]};                    \
    const float cc[4] = {R1[xm1], vc.x, vc.y, R1[xp2]};                    \
    const float cp[4] = {R2[xm1], vp.x, vp.y, R2[xp2]};                    \
    float s_[4], d_[4];                                                    \
    _Pragma("unroll") for (int i = 0; i < 4; ++i) {                        \
        s_[i] = fmaf(2.0f, cc[i], cm[i] + cp[i]);                          \
        d_[i] = cp[i] - cm[i]; }                                           \
    /* raw features; 1/8, 1/16 and -ident folded into weights */           \
    const float2 idn2 = make_float2(cc[1], cc[2]);                         \
    const float2 sx2  = make_float2(s_[2] - s_[0], s_[3] - s_[1]);         \
    const float2 sy2  = make_float2(fmaf(2.0f, d_[1], d_[0] + d_[2]),      \
                                    fmaf(2.0f, d_[2], d_[1] + d_[3]));     \
    const float2 lp2  = make_float2(fmaf(2.0f, s_[1], s_[0] + s_[2]),      \
                                    fmaf(2.0f, s_[2], s_[1] + s_[3]));     \
    const float2* wch = wd + (ch) * 64;                                    \
    _Pragma("unroll") for (int h = 0; h < HID; ++h) {                      \
        PKFMA_S(acc[h], wch[h * 4 + 0], idn2);                             \
        PKFMA_S(acc[h], wch[h * 4 + 1], sx2);                              \
        PKFMA_S(acc[h], wch[h * 4 + 2], sy2);                              \
        PKFMA_S(acc[h], wch[h * 4 + 3], lp2); } } while (0)

    float2 acc[HID];                      // 32 VGPRs, static idx (unrolled)
#pragma unroll
    for (int h = 0; h < HID; ++h) {
        const float bv = w1b[h];          // uniform -> s_load
        acc[h] = make_float2(bv, bv);
    }

    // ---- 4-phase pipeline: stage next 2 channels, compute current 2 ----
    STAGE(0, 0);
    __syncthreads();
    STAGE(2, BUF); COMPCH(0, 0, 0);   COMPCH(1, 1, 0);   __syncthreads();
    STAGE(4, 0);   COMPCH(2, 0, BUF); COMPCH(3, 1, BUF); __syncthreads();
    STAGE(6, BUF); COMPCH(4, 0, 0);   COMPCH(5, 1, 0);   __syncthreads();
                   COMPCH(6, 0, BUF); COMPCH(7, 1, BUF);

#undef STAGE
#undef COMPCH

    // ReLU
#pragma unroll
    for (int h = 0; h < HID; ++h) {
        acc[h].x = fmaxf(acc[h].x, 0.0f);
        acc[h].y = fmaxf(acc[h].y, 0.0f);
    }

    const float2* w2d = wd + 512;
    float* ob = out + (size_t)b * C * HW;

    // epilogue: pipelined residual loads (prefetch o+1 under o's 16 pk_fma)
    float2 xo = *(const float2*)(xb + pix);
#pragma unroll
    for (int o = 0; o < C; ++o) {
        float2 xn;
        if (o + 1 < C) xn = *(const float2*)(xb + (o + 1) * HW + pix);
        float2 v = make_float2(0.0f, 0.0f);
#pragma unroll
        for (int h = 0; h < HID; ++h)
            PKFMA_S(v, w2d[o * 16 + h], acc[h]);
        PKFMA_V(xo, v, mf);               // xo += v * mask
        *(float2*)(ob + o * HW + pix) = xo;
        xo = xn;
    }
}

extern "C" void kernel_launch(void* const* d_in, const int* in_sizes, int n_in,
                              void* d_out, int out_size, void* d_ws, size_t ws_size,
                              hipStream_t stream) {
    const float* x    = (const float*)d_in[0];
    const float* w1w  = (const float*)d_in[1];
    const float* w1b  = (const float*)d_in[2];
    const float* w2w  = (const float*)d_in[3];
    const int*   mask = (const int*)d_in[4];
    float* out = (float*)d_out;
    float2* wd = (float2*)d_ws;           // 640 * 8 B = 5 KiB scratch

    hipLaunchKernelGGL(repack_weights, dim3(3), dim3(256), 0, stream,
                       w1w, w2w, wd);
    hipLaunchKernelGGL(nca_step_kernel, dim3(B * H / 2), dim3(512), 0, stream,
                       x, w1b, mask, out, wd);
}

// Round 13
// 90.927 us; speedup vs baseline: 1.1872x; 1.0667x over previous
//
#include <hip/hip_runtime.h>
#include <stdint.h>

// Fused NCA step via MATRIX CORES — verified-primitives-only build.
// perception(4 fixed 3x3, wrap) -> 1x1 conv 32->16 +b+ReLU -> 1x1 conv 16->8
// -> x + y*mask.
// R13: R11 (absmax 2.2 = max|y|) and R12 (NaN) differed only in conv2's
// instruction form -> the unverified primitives (inline-asm v_cvt_pk_bf16_f32,
// 16x16x16 MFMA asm/builtin) are the failure. This build uses ONLY
// __builtin_amdgcn_mfma_f32_16x16x32_bf16 (m89-verified) and plain-C bf16
// conversions:
//  - conv1: D1[16hid x 16px] = W1eff[16 x K32] x F[K32 x 16px], hi/lo split
//    (3 MFMAs) => ~fp32 accuracy. Bias preloaded into the accumulator.
//  - conv2: SAME K=32 builtin with zero-padding: A=W2 (och rows 8..15 = 0,
//    lane elements j>=4 = 0), B = {relu(acc[0..3]), 0x4}. Lane-group g holds
//    hid 4g+r in BOTH fragments -> result exact under any symmetric A/B k-map
//    (the only layout assumption, shared with conv1).
// Block = 512 thr = row pair; LDS: 8ch x 4 halo-padded rows + 2 mask rows
// (71 KB); stage via global_load_lds -> barrier -> compute.

constexpr int B = 16, C = 8, H = 512, W = 512, HID = 16;
constexpr int HW = H * W;

// LDS geometry (floats). Rows halo-padded: [pad3][lhalo][512 data][rhalo]
// data col c at idx c+4; left halo idx3 = col 511; right halo idx516 = col 0.
constexpr int ROWF = 520;            // 2080 B, 16B-aligned rows
constexpr int CHF  = 4 * ROWF + 8;   // 2088: +8 pad spreads channels over banks
constexpr int XTOT = 8 * CHF;        // 16704
constexpr int MOFF = XTOT;           // 2 mask rows (raw int bits)
constexpr int LDSF = XTOT + 2 * 512; // 17728 floats = 70912 B

typedef __attribute__((ext_vector_type(8))) short bf16x8;
typedef __attribute__((ext_vector_type(4))) float f32x4;
typedef const __attribute__((address_space(1))) void* as1cp;
typedef __attribute__((address_space(3))) void* as3p;

__device__ __host__ inline uint32_t bf16rne(float f) {   // 16-bit result in low bits
    const uint32_t u = __float_as_uint(f);
    return (u + 0x7fffu + ((u >> 16) & 1u)) >> 16;
}
__device__ inline float bf16tof(uint32_t hs) { return __uint_as_float(hs << 16); }

// d_ws layout (u32 units):
//  [0..255]   W1eff hi A-frag: lane t holds elems j=0..7 of (row=t&15, grp=t>>4)
//  [256..511] W1eff lo A-frag
//  [512..767] W2 A-frag, K=32 zero-padded: j<4 -> w2[och=t&15][ (t>>4)*4+j ]
//             (0 for och>=8), j>=4 -> 0
//  [768..783] bias (f32)
__global__ void repack(const float* __restrict__ w1w,
                       const float* __restrict__ w1b,
                       const float* __restrict__ w2w,
                       float* __restrict__ wdf) {
    uint32_t* wd = (uint32_t*)wdf;
    const int t = threadIdx.x;
    if (t >= 64) return;
    const int h = t & 15, kg = t >> 4;
    uint32_t whi[4] = {0, 0, 0, 0}, wlo[4] = {0, 0, 0, 0}, w2f[4] = {0, 0, 0, 0};
    for (int j = 0; j < 8; ++j) {
        const int k = kg * 8 + j, ch = k >> 2, f = k & 3;
        const float* wr = w1w + h * 32 + ch * 4;
        // fold perception scales + lap's -ident into W1
        const float we = (f == 0) ? (wr[0] - wr[3])
                       : (f == 3) ? wr[3] * 0.0625f
                                  : wr[f] * 0.125f;
        const uint32_t hs = bf16rne(we);
        const uint32_t ls = bf16rne(we - bf16tof(hs));
        whi[j >> 1] |= hs << (16 * (j & 1));
        wlo[j >> 1] |= ls << (16 * (j & 1));
    }
    for (int j = 0; j < 4; ++j) {        // conv2 frag: j>=4 stays zero
        const float v = (h < 8) ? w2w[h * 16 + kg * 4 + j] : 0.0f;
        w2f[j >> 1] |= bf16rne(v) << (16 * (j & 1));
    }
    for (int q = 0; q < 4; ++q) {
        wd[t * 4 + q]       = whi[q];
        wd[256 + t * 4 + q] = wlo[q];
        wd[512 + t * 4 + q] = w2f[q];
    }
    if (t < 16) wdf[768 + t] = w1b[t];
}

__global__ __launch_bounds__(512, 4) void nca_step_kernel(
    const float* __restrict__ x,
    const int*   __restrict__ mask,
    float*       __restrict__ out,
    const float* __restrict__ wdf)
{
    __shared__ float S[LDSF];

    // block = one row PAIR; XCD-bijective swizzle (4096 = 8 * 512)
    const int bid = blockIdx.x;
    const int l   = (bid & 7) * 512 + (bid >> 3);
    const int b   = l >> 8;
    const int y0  = (l & 255) << 1;

    const int tid  = threadIdx.x;
    const int lane = tid & 63;
    const int wv   = tid >> 6;            // wave 0..7

    const float* xb = x + (size_t)b * C * HW;
    const int*   mb = mask + (size_t)b * HW;

    // per-lane constant fragments (same for every wave)
    union { uint4 u; bf16x8 v; } whiU, wloU, w2U;
    whiU.u = ((const uint4*)wdf)[lane];
    wloU.u = ((const uint4*)wdf)[64 + lane];
    w2U.u  = ((const uint4*)wdf)[128 + lane];
    const f32x4 bias4 = ((const f32x4*)(wdf + 768))[lane >> 4];

    // ---- stage: 8ch x 4 rows (y0-1..y0+2) + 2 mask rows, 68 x 1KB DMAs ----
    for (int c = wv; c < 68; c += 8) {
        if (c < 64) {
            const int r = c >> 1, hf = c & 1;
            const int ch = r >> 2, rs = r & 3;
            const int grow = (y0 - 1 + rs) & (H - 1);
            const float* src = xb + ch * HW + grow * W + hf * 256 + lane * 4;
            float* dst = S + ch * CHF + rs * ROWF + 4 + hf * 256;
            __builtin_amdgcn_global_load_lds((as1cp)src, (as3p)dst, 16, 0, 0);
        } else {
            const int mr = (c - 64) >> 1, hf = c & 1;
            const int* src = mb + (y0 + mr) * W + hf * 256 + lane * 4;
            float* dst = S + MOFF + mr * 512 + hf * 256;
            __builtin_amdgcn_global_load_lds((as1cp)src, (as3p)dst, 16, 0, 0);
        }
    }
    __syncthreads();                      // drains the DMAs
    if (tid < 64) {                       // halo fill (wrap columns)
        const int r = tid >> 1;
        float* rb = S + (r >> 2) * CHF + (r & 3) * ROWF;
        if (tid & 1) rb[516] = rb[4];     // right halo = col 0
        else         rb[3]   = rb[515];   // left halo  = col 511
    }
    __syncthreads();

    // ---- compute: wave wv -> row y0+(wv>>2), groups (wv&3)+4i ----
    const int rel = wv >> 2;
    const int y   = y0 + rel;
    const int grp = lane >> 4;            // lane-group: channels 2grp, 2grp+1
    const int p   = lane & 15;            // px within group
    const int chA = grp * 2;
    float* ob = out + (size_t)b * C * HW;

#pragma unroll 1
    for (int i = 0; i < 8; ++i) {
        const int g  = (wv & 3) + i * 4;
        const int px = g * 16 + p;
        const int ci = px + 3;            // LDS idx of col px-1

        // features in fragment element order: j=0..3 ch=chA, j=4..7 ch=chA+1,
        // each {ident, sx_raw, sy_raw, lap_raw} (scales folded into W1)
        float f_[8];
#pragma unroll
        for (int cc = 0; cc < 2; ++cc) {
            const float* R0 = S + (chA + cc) * CHF + rel * ROWF + ci;
            const float* R1 = R0 + ROWF;
            const float* R2 = R1 + ROWF;
            const float a0 = R0[0], a1 = R0[1], a2 = R0[2];
            const float b0 = R1[0], b1 = R1[1], b2 = R1[2];
            const float c0 = R2[0], c1 = R2[1], c2 = R2[2];
            const float s0 = fmaf(2.f, b0, a0 + c0);
            const float s1 = fmaf(2.f, b1, a1 + c1);
            const float s2 = fmaf(2.f, b2, a2 + c2);
            const float d0 = c0 - a0, d1 = c1 - a1, d2 = c2 - a2;
            f_[cc * 4 + 0] = b1;
            f_[cc * 4 + 1] = s2 - s0;
            f_[cc * 4 + 2] = fmaf(2.f, d1, d0 + d2);
            f_[cc * 4 + 3] = fmaf(2.f, s1, s0 + s2);
        }

        // bf16 hi/lo split, plain-C RNE (no asm), fully static indices
        uint32_t hw_[4] = {0, 0, 0, 0}, lw_[4] = {0, 0, 0, 0};
#pragma unroll
        for (int j = 0; j < 8; ++j) {
            const uint32_t hs = bf16rne(f_[j]);
            const uint32_t ls = bf16rne(f_[j] - bf16tof(hs));
            hw_[j >> 1] |= hs << (16 * (j & 1));
            lw_[j >> 1] |= ls << (16 * (j & 1));
        }
        union { uint32_t u[4]; bf16x8 v; } bh = {{hw_[0], hw_[1], hw_[2], hw_[3]}};
        union { uint32_t u[4]; bf16x8 v; } bl = {{lw_[0], lw_[1], lw_[2], lw_[3]}};

        // conv1: W*F ~= Whi*Fhi + Whi*Flo + Wlo*Fhi   (bias preloaded in C)
        f32x4 acc = bias4;
        acc = __builtin_amdgcn_mfma_f32_16x16x32_bf16(whiU.v, bh.v, acc, 0, 0, 0);
        acc = __builtin_amdgcn_mfma_f32_16x16x32_bf16(whiU.v, bl.v, acc, 0, 0, 0);
        acc = __builtin_amdgcn_mfma_f32_16x16x32_bf16(wloU.v, bh.v, acc, 0, 0, 0);

        // conv2 via the SAME verified K=32 builtin, zero-padded fragments:
        // B elems j<4 = relu(acc[j]) (= hid 4*grp+j), j>=4 = 0; A likewise.
        const uint32_t p0 = bf16rne(fmaxf(acc[0], 0.f))
                          | (bf16rne(fmaxf(acc[1], 0.f)) << 16);
        const uint32_t p1 = bf16rne(fmaxf(acc[2], 0.f))
                          | (bf16rne(fmaxf(acc[3], 0.f)) << 16);
        union { uint32_t u[4]; bf16x8 v; } b2 = {{p0, p1, 0, 0}};
        f32x4 d2 = {0.f, 0.f, 0.f, 0.f};
        d2 = __builtin_amdgcn_mfma_f32_16x16x32_bf16(w2U.v, b2.v, d2, 0, 0, 0);

        // epilogue: lanes 0..31 hold och=(lane>>4)*4+r (rows 8..15 are pad)
        if (lane < 32) {
            const float mfv =
                (float)((const int*)(S + MOFF))[rel * 512 + px];
            const int och0 = grp * 4;
            float* op = ob + y * W + px;
#pragma unroll
            for (int r = 0; r < 4; ++r) {
                const float xv =
                    S[(och0 + r) * CHF + (rel + 1) * ROWF + 4 + px];
                op[(och0 + r) * HW] = fmaf(d2[r], mfv, xv);
            }
        }
    }
}

extern "C" void kernel_launch(void* const* d_in, const int* in_sizes, int n_in,
                              void* d_out, int out_size, void* d_ws, size_t ws_size,
                              hipStream_t stream) {
    const float* x    = (const float*)d_in[0];
    const float* w1w  = (const float*)d_in[1];
    const float* w1b  = (const float*)d_in[2];
    const float* w2w  = (const float*)d_in[3];
    const int*   mask = (const int*)d_in[4];
    float* out = (float*)d_out;
    float* wdf = (float*)d_ws;            // 3.1 KB of fragment scratch

    hipLaunchKernelGGL(repack, dim3(1), dim3(64), 0, stream,
                       w1w, w1b, w2w, wdf);
    hipLaunchKernelGGL(nca_step_kernel, dim3(B * H / 2), dim3(512), 0, stream,
                       x, mask, out, wdf);
}

// Round 14
// 80.670 us; speedup vs baseline: 1.3382x; 1.1272x over previous
//
#include <hip/hip_runtime.h>
#include <stdint.h>

// Fused NCA step via MATRIX CORES — verified-primitives-only build.
// perception(4 fixed 3x3, wrap) -> 1x1 conv 32->16 +b+ReLU -> 1x1 conv 16->8
// -> x + y*mask.
// R14 = R13 (passed, 91us) minus its VALU hot spot: R13's plain-C bf16 hi/lo
// split was ~60% of per-iter VALU (96 of ~153 ops). Changes:
//  - features single-bf16 (drop F lo-split): W1 stays hi/lo (precomputed) so
//    conv1 = 2 MFMAs; error budget +~0.02 on measured 0.031 (thr 0.114).
//  - RNE pair-pack via u+0x7fff+((u>>16)&1) then __builtin_amdgcn_perm
//    (v_perm_b32 merges the two high halves): 5 VALU/pair vs ~24.
//  - #pragma unroll 2 on the i-loop (VGPR 52 -> headroom to 128).
// All staging / halo / fragment layouts byte-identical to R13 (proven).

constexpr int B = 16, C = 8, H = 512, W = 512, HID = 16;
constexpr int HW = H * W;

// LDS geometry (floats). Rows halo-padded: [pad3][lhalo][512 data][rhalo]
// data col c at idx c+4; left halo idx3 = col 511; right halo idx516 = col 0.
constexpr int ROWF = 520;            // 2080 B, 16B-aligned rows
constexpr int CHF  = 4 * ROWF + 8;   // 2088: +8 pad spreads channels over banks
constexpr int XTOT = 8 * CHF;        // 16704
constexpr int MOFF = XTOT;           // 2 mask rows (raw int bits)
constexpr int LDSF = XTOT + 2 * 512; // 17728 floats = 70912 B

typedef __attribute__((ext_vector_type(8))) short bf16x8;
typedef __attribute__((ext_vector_type(4))) float f32x4;
typedef const __attribute__((address_space(1))) void* as1cp;
typedef __attribute__((address_space(3))) void* as3p;

__device__ __host__ inline uint32_t bf16rne(float f) {   // result in low 16
    const uint32_t u = __float_as_uint(f);
    return (u + 0x7fffu + ((u >> 16) & 1u)) >> 16;
}
__device__ inline float bf16tof(uint32_t hs) { return __uint_as_float(hs << 16); }

// pack {bf16(a) lo, bf16(b) hi} : 2x(RNE round) + 1 v_perm_b32
__device__ inline uint32_t pkbf(float a, float b) {
    const uint32_t ua = __float_as_uint(a);
    const uint32_t ub = __float_as_uint(b);
    const uint32_t ra = ua + 0x7fffu + ((ua >> 16) & 1u);
    const uint32_t rb = ub + 0x7fffu + ((ub >> 16) & 1u);
    return __builtin_amdgcn_perm(rb, ra, 0x07060302u);   // {ra.hi16, rb.hi16}
}

// d_ws layout (u32 units):
//  [0..255]   W1eff hi A-frag: lane t holds elems j=0..7 of (row=t&15, grp=t>>4)
//  [256..511] W1eff lo A-frag
//  [512..767] W2 A-frag, K=32 zero-padded: j<4 -> w2[och=t&15][ (t>>4)*4+j ]
//             (0 for och>=8), j>=4 -> 0
//  [768..783] bias (f32)
__global__ void repack(const float* __restrict__ w1w,
                       const float* __restrict__ w1b,
                       const float* __restrict__ w2w,
                       float* __restrict__ wdf) {
    uint32_t* wd = (uint32_t*)wdf;
    const int t = threadIdx.x;
    if (t >= 64) return;
    const int h = t & 15, kg = t >> 4;
    uint32_t whi[4] = {0, 0, 0, 0}, wlo[4] = {0, 0, 0, 0}, w2f[4] = {0, 0, 0, 0};
    for (int j = 0; j < 8; ++j) {
        const int k = kg * 8 + j, ch = k >> 2, f = k & 3;
        const float* wr = w1w + h * 32 + ch * 4;
        // fold perception scales + lap's -ident into W1
        const float we = (f == 0) ? (wr[0] - wr[3])
                       : (f == 3) ? wr[3] * 0.0625f
                                  : wr[f] * 0.125f;
        const uint32_t hs = bf16rne(we);
        const uint32_t ls = bf16rne(we - bf16tof(hs));
        whi[j >> 1] |= hs << (16 * (j & 1));
        wlo[j >> 1] |= ls << (16 * (j & 1));
    }
    for (int j = 0; j < 4; ++j) {        // conv2 frag: j>=4 stays zero
        const float v = (h < 8) ? w2w[h * 16 + kg * 4 + j] : 0.0f;
        w2f[j >> 1] |= bf16rne(v) << (16 * (j & 1));
    }
    for (int q = 0; q < 4; ++q) {
        wd[t * 4 + q]       = whi[q];
        wd[256 + t * 4 + q] = wlo[q];
        wd[512 + t * 4 + q] = w2f[q];
    }
    if (t < 16) wdf[768 + t] = w1b[t];
}

__global__ __launch_bounds__(512, 4) void nca_step_kernel(
    const float* __restrict__ x,
    const int*   __restrict__ mask,
    float*       __restrict__ out,
    const float* __restrict__ wdf)
{
    __shared__ float S[LDSF];

    // block = one row PAIR; XCD-bijective swizzle (4096 = 8 * 512)
    const int bid = blockIdx.x;
    const int l   = (bid & 7) * 512 + (bid >> 3);
    const int b   = l >> 8;
    const int y0  = (l & 255) << 1;

    const int tid  = threadIdx.x;
    const int lane = tid & 63;
    const int wv   = tid >> 6;            // wave 0..7

    const float* xb = x + (size_t)b * C * HW;
    const int*   mb = mask + (size_t)b * HW;

    // per-lane constant fragments (same for every wave)
    union { uint4 u; bf16x8 v; } whiU, wloU, w2U;
    whiU.u = ((const uint4*)wdf)[lane];
    wloU.u = ((const uint4*)wdf)[64 + lane];
    w2U.u  = ((const uint4*)wdf)[128 + lane];
    const f32x4 bias4 = ((const f32x4*)(wdf + 768))[lane >> 4];

    // ---- stage: 8ch x 4 rows (y0-1..y0+2) + 2 mask rows, 68 x 1KB DMAs ----
    for (int c = wv; c < 68; c += 8) {
        if (c < 64) {
            const int r = c >> 1, hf = c & 1;
            const int ch = r >> 2, rs = r & 3;
            const int grow = (y0 - 1 + rs) & (H - 1);
            const float* src = xb + ch * HW + grow * W + hf * 256 + lane * 4;
            float* dst = S + ch * CHF + rs * ROWF + 4 + hf * 256;
            __builtin_amdgcn_global_load_lds((as1cp)src, (as3p)dst, 16, 0, 0);
        } else {
            const int mr = (c - 64) >> 1, hf = c & 1;
            const int* src = mb + (y0 + mr) * W + hf * 256 + lane * 4;
            float* dst = S + MOFF + mr * 512 + hf * 256;
            __builtin_amdgcn_global_load_lds((as1cp)src, (as3p)dst, 16, 0, 0);
        }
    }
    __syncthreads();                      // drains the DMAs
    if (tid < 64) {                       // halo fill (wrap columns)
        const int r = tid >> 1;
        float* rb = S + (r >> 2) * CHF + (r & 3) * ROWF;
        if (tid & 1) rb[516] = rb[4];     // right halo = col 0
        else         rb[3]   = rb[515];   // left halo  = col 511
    }
    __syncthreads();

    // ---- compute: wave wv -> row y0+(wv>>2), groups (wv&3)+4i ----
    const int rel = wv >> 2;
    const int y   = y0 + rel;
    const int grp = lane >> 4;            // lane-group: channels 2grp, 2grp+1
    const int p   = lane & 15;            // px within group
    const int chA = grp * 2;
    float* ob = out + (size_t)b * C * HW;

#pragma unroll 2
    for (int i = 0; i < 8; ++i) {
        const int g  = (wv & 3) + i * 4;
        const int px = g * 16 + p;
        const int ci = px + 3;            // LDS idx of col px-1

        // features in fragment element order: j=0..3 ch=chA, j=4..7 ch=chA+1,
        // each {ident, sx_raw, sy_raw, lap_raw} (scales folded into W1)
        float f_[8];
#pragma unroll
        for (int cc = 0; cc < 2; ++cc) {
            const float* R0 = S + (chA + cc) * CHF + rel * ROWF + ci;
            const float* R1 = R0 + ROWF;
            const float* R2 = R1 + ROWF;
            const float a0 = R0[0], a1 = R0[1], a2 = R0[2];
            const float b0 = R1[0], b1 = R1[1], b2 = R1[2];
            const float c0 = R2[0], c1 = R2[1], c2 = R2[2];
            const float s0 = fmaf(2.f, b0, a0 + c0);
            const float s1 = fmaf(2.f, b1, a1 + c1);
            const float s2 = fmaf(2.f, b2, a2 + c2);
            const float d0 = c0 - a0, d1 = c1 - a1, d2 = c2 - a2;
            f_[cc * 4 + 0] = b1;
            f_[cc * 4 + 1] = s2 - s0;
            f_[cc * 4 + 2] = fmaf(2.f, d1, d0 + d2);
            f_[cc * 4 + 3] = fmaf(2.f, s1, s0 + s2);
        }

        // single-bf16 feature fragment: 4x pkbf (RNE + v_perm)
        union { uint32_t u[4]; bf16x8 v; } bh = {{
            pkbf(f_[0], f_[1]), pkbf(f_[2], f_[3]),
            pkbf(f_[4], f_[5]), pkbf(f_[6], f_[7])}};

        // conv1: W*F = (Whi + Wlo)*F   (W split exact; bias preloaded in C)
        f32x4 acc = bias4;
        acc = __builtin_amdgcn_mfma_f32_16x16x32_bf16(whiU.v, bh.v, acc, 0, 0, 0);
        acc = __builtin_amdgcn_mfma_f32_16x16x32_bf16(wloU.v, bh.v, acc, 0, 0, 0);

        // conv2 via the SAME verified K=32 builtin, zero-padded fragments:
        // B elems j<4 = relu(acc[j]) (= hid 4*grp+j), j>=4 = 0; A likewise.
        union { uint32_t u[4]; bf16x8 v; } b2 = {{
            pkbf(fmaxf(acc[0], 0.f), fmaxf(acc[1], 0.f)),
            pkbf(fmaxf(acc[2], 0.f), fmaxf(acc[3], 0.f)), 0, 0}};
        f32x4 d2 = {0.f, 0.f, 0.f, 0.f};
        d2 = __builtin_amdgcn_mfma_f32_16x16x32_bf16(w2U.v, b2.v, d2, 0, 0, 0);

        // epilogue: lanes 0..31 hold och=(lane>>4)*4+r (rows 8..15 are pad)
        if (lane < 32) {
            const float mfv =
                (float)((const int*)(S + MOFF))[rel * 512 + px];
            const int och0 = grp * 4;
            float* op = ob + y * W + px;
#pragma unroll
            for (int r = 0; r < 4; ++r) {
                const float xv =
                    S[(och0 + r) * CHF + (rel + 1) * ROWF + 4 + px];
                op[(och0 + r) * HW] = fmaf(d2[r], mfv, xv);
            }
        }
    }
}

extern "C" void kernel_launch(void* const* d_in, const int* in_sizes, int n_in,
                              void* d_out, int out_size, void* d_ws, size_t ws_size,
                              hipStream_t stream) {
    const float* x    = (const float*)d_in[0];
    const float* w1w  = (const float*)d_in[1];
    const float* w1b  = (const float*)d_in[2];
    const float* w2w  = (const float*)d_in[3];
    const int*   mask = (const int*)d_in[4];
    float* out = (float*)d_out;
    float* wdf = (float*)d_ws;            // 3.1 KB of fragment scratch

    hipLaunchKernelGGL(repack, dim3(1), dim3(64), 0, stream,
                       w1w, w1b, w2w, wdf);
    hipLaunchKernelGGL(nca_step_kernel, dim3(B * H / 2), dim3(512), 0, stream,
                       x, mask, out, wdf);
}